// Round 10
// baseline (590.830 us; speedup 1.0000x reference)
//
#include <hip/hip_runtime.h>
#include <hip/hip_bf16.h>
#include <math.h>

// Problem constants (match reference setup_inputs)
#define NN   100000
#define NE   1600000
#define FIN  128
#define HID  32
#define NHEADS 4
#define NCLS 10

typedef unsigned int uint32;
typedef __fp16 half2_t __attribute__((ext_vector_type(2)));

// pack 2 fp32 -> packed fp16 pair (v_cvt_pkrtz_f16_f32, 1 inst)
__device__ __forceinline__ uint32 packh2(float a, float b) {
    half2_t h = __builtin_amdgcn_cvt_pkrtz(a, b);
    return __builtin_bit_cast(uint32, h);
}
__device__ __forceinline__ float h_lo(uint32 v) {
    return (float)__builtin_bit_cast(half2_t, v)[0];
}
__device__ __forceinline__ float h_hi(uint32 v) {
    return (float)__builtin_bit_cast(half2_t, v)[1];
}
// 4 channels of one edge: compiler lowers cvt+fma to v_fma_mix_f32
__device__ __forceinline__ void fmah4(float* acc, uint2 v, float w) {
    acc[0] = fmaf(h_lo(v.x), w, acc[0]);
    acc[1] = fmaf(h_hi(v.x), w, acc[1]);
    acc[2] = fmaf(h_lo(v.y), w, acc[2]);
    acc[3] = fmaf(h_hi(v.y), w, acc[3]);
}

// ---------------------------------------------------------------------------
// CSR build kernels
// ---------------------------------------------------------------------------
__global__ void zero_i32(int* __restrict__ p, int n) {
    int i = blockIdx.x * blockDim.x + threadIdx.x;
    if (i < n) p[i] = 0;
}

// histogram + per-edge rank in one pass: the atomic's return value IS the
// rank of edge j within its dst segment. 4 edges/thread for atomic ILP.
__global__ void hist_rank_kernel(const int* __restrict__ dst, int* __restrict__ cnt,
                                 int* __restrict__ rank, int e) {
    const int t0 = blockIdx.x * (blockDim.x * 4) + threadIdx.x;
    int d[4];
    bool a[4];
#pragma unroll
    for (int k = 0; k < 4; ++k) {
        const int j = t0 + k * 256;
        a[k] = (j < e);
        d[k] = a[k] ? dst[j] : 0;
    }
    int r[4];
#pragma unroll
    for (int k = 0; k < 4; ++k)
        if (a[k]) r[k] = atomicAdd(&cnt[d[k]], 1);
#pragma unroll
    for (int k = 0; k < 4; ++k) {
        const int j = t0 + k * 256;
        if (a[k]) rank[j] = r[k];
    }
}

__global__ void scan_block_sums(const int* __restrict__ cnt, int* __restrict__ bsum, int n) {
    __shared__ int sm[256];
    int i = blockIdx.x * 256 + threadIdx.x;
    int v = (i < n) ? cnt[i] : 0;
    sm[threadIdx.x] = v;
    __syncthreads();
    for (int off = 128; off > 0; off >>= 1) {
        if (threadIdx.x < off) sm[threadIdx.x] += sm[threadIdx.x + off];
        __syncthreads();
    }
    if (threadIdx.x == 0) bsum[blockIdx.x] = sm[0];
}

__global__ void scan_single(const int* __restrict__ bsum, int* __restrict__ boff, int nb) {
    __shared__ int sm[512];
    int t = threadIdx.x;
    int v = (t < nb) ? bsum[t] : 0;
    sm[t] = v;
    __syncthreads();
    for (int off = 1; off < 512; off <<= 1) {
        int u = (t >= off) ? sm[t - off] : 0;
        __syncthreads();
        sm[t] += u;
        __syncthreads();
    }
    if (t < nb) boff[t] = sm[t] - v;   // exclusive
}

__global__ void scan_final(const int* __restrict__ cnt, const int* __restrict__ boff,
                           int* __restrict__ rowptr, int n) {
    __shared__ int sm[256];
    int i = blockIdx.x * 256 + threadIdx.x;
    int v = (i < n) ? cnt[i] : 0;
    sm[threadIdx.x] = v;
    __syncthreads();
    for (int off = 1; off < 256; off <<= 1) {
        int u = (threadIdx.x >= off) ? sm[threadIdx.x - off] : 0;
        __syncthreads();
        sm[threadIdx.x] += u;
        __syncthreads();
    }
    int incl = sm[threadIdx.x];
    int excl = incl - v;
    if (i < n) rowptr[i] = boff[blockIdx.x] + excl;
    if (i == n - 1) rowptr[n] = boff[blockIdx.x] + incl;  // == E
}

// atomic-free scatter: position = rowptr[dst] + rank. 4 edges/thread.
__global__ void scatter_kernel(const int* __restrict__ src, const int* __restrict__ dst,
                               const int* __restrict__ rank, const int* __restrict__ rowptr,
                               int* __restrict__ esrc, int e) {
    const int t0 = blockIdx.x * (blockDim.x * 4) + threadIdx.x;
#pragma unroll
    for (int k = 0; k < 4; ++k) {
        const int j = t0 + k * 256;
        if (j < e) {
            const int d = dst[j];
            esrc[rowptr[d] + rank[j]] = src[j];
        }
    }
}

// ---------------------------------------------------------------------------
// LDS-tiled GEMM + fused attention-logit epilogue.
//   Outh (fp16-packed)  = RTZ(X @ W)                [N, FOUT/2 uints]
//   alS[n,h] = sum_c h[n,h,c]*a_src[h,c]  (fp32, exact — from acc registers)
//   alD[n,h] = sum_c h[n,h,c]*a_dst[h,c]
// As rows padded to 132 floats (16B-aligned rows -> ds_read_b128 A reads).
// ---------------------------------------------------------------------------
template <int FOUT, int H>
__global__ __launch_bounds__(256) void gemm_tiled(const float* __restrict__ X,
                                                  const float* __restrict__ Wm,
                                                  const float* __restrict__ a_s,
                                                  const float* __restrict__ a_d,
                                                  float* __restrict__ alS,
                                                  float* __restrict__ alD,
                                                  uint32* __restrict__ Outh, int n) {
    constexpr int K   = 128;
    constexpr int KC  = 32;
    constexpr int MT  = 128;
    constexpr int CPT = FOUT / 16;            // 8 (FOUT=128) or 2 (FOUT=32)
    constexpr int C   = FOUT / H;             // 32
    constexpr int TPH = 16 / H;               // tx-threads per head: 4 or 16
    __shared__ __align__(16) float As[KC][132];   // row stride 132 -> rows 16B aligned
    __shared__ __align__(16) float Bs[KC][FOUT];

    const int t   = threadIdx.x;
    const int tx  = t & 15;
    const int ty  = t >> 4;
    const int row0 = blockIdx.x * MT;

    float acc[8][CPT];
#pragma unroll
    for (int i = 0; i < 8; ++i)
#pragma unroll
        for (int j = 0; j < CPT; ++j) acc[i][j] = 0.f;

    for (int kc = 0; kc < K; kc += KC) {
#pragma unroll
        for (int i = 0; i < 4; ++i) {
            const int l  = t + i * 256;
            const int ar = l >> 3;
            const int af = l & 7;
            int grow = row0 + ar;
            if (grow >= n) grow = n - 1;
            const float4 v = *(const float4*)(X + (size_t)grow * K + kc + af * 4);
            As[af * 4 + 0][ar] = v.x;
            As[af * 4 + 1][ar] = v.y;
            As[af * 4 + 2][ar] = v.z;
            As[af * 4 + 3][ar] = v.w;
        }
        constexpr int BF4 = KC * FOUT / 4;
#pragma unroll
        for (int i = 0; i < BF4 / 256; ++i) {
            const int l   = t + i * 256;
            const int br  = l / (FOUT / 4);
            const int bc4 = l % (FOUT / 4);
            const float4 v = *(const float4*)(Wm + (size_t)(kc + br) * FOUT + bc4 * 4);
            *(float4*)&Bs[br][bc4 * 4] = v;
        }
        __syncthreads();

#pragma unroll 8
        for (int k = 0; k < KC; ++k) {
            const float4 a0 = *(const float4*)&As[k][ty * 8];
            const float4 a1 = *(const float4*)&As[k][ty * 8 + 4];
            const float a[8] = {a0.x, a0.y, a0.z, a0.w, a1.x, a1.y, a1.z, a1.w};
            float b[CPT];
            if constexpr (CPT == 8) {
                const float4 b0 = *(const float4*)&Bs[k][tx * 8];
                const float4 b1 = *(const float4*)&Bs[k][tx * 8 + 4];
                b[0] = b0.x; b[1] = b0.y; b[2] = b0.z; b[3] = b0.w;
                b[4] = b1.x; b[5] = b1.y; b[6] = b1.z; b[7] = b1.w;
            } else {
                const float2 b0 = *(const float2*)&Bs[k][tx * 2];
                b[0] = b0.x; b[1] = b0.y;
            }
#pragma unroll
            for (int i = 0; i < 8; ++i)
#pragma unroll
                for (int j = 0; j < CPT; ++j)
                    acc[i][j] = fmaf(a[i], b[j], acc[i][j]);
        }
        __syncthreads();
    }

    // ---- fused al epilogue: my cols all belong to head h ----
    const int h     = tx / TPH;
    const int cbase = (tx % TPH) * CPT;       // col offset within head
    float av[CPT], dv[CPT];
#pragma unroll
    for (int j = 0; j < CPT; ++j) {
        av[j] = a_s[h * C + cbase + j];
        dv[j] = a_d[h * C + cbase + j];
    }

#pragma unroll
    for (int i = 0; i < 8; ++i) {
        const int grow = row0 + ty * 8 + i;
        // fp16 store
        if (grow < n) {
            uint32* bp = Outh + ((size_t)grow * FOUT + tx * CPT) / 2;
            if constexpr (CPT == 8) {
                uint4 pb;
                pb.x = packh2(acc[i][0], acc[i][1]);
                pb.y = packh2(acc[i][2], acc[i][3]);
                pb.z = packh2(acc[i][4], acc[i][5]);
                pb.w = packh2(acc[i][6], acc[i][7]);
                *(uint4*)bp = pb;
            } else {
                *bp = packh2(acc[i][0], acc[i][1]);
            }
        }
        // partial logit dots + reduce across the TPH lanes sharing this head
        float ps = 0.f, pd = 0.f;
#pragma unroll
        for (int j = 0; j < CPT; ++j) {
            ps = fmaf(acc[i][j], av[j], ps);
            pd = fmaf(acc[i][j], dv[j], pd);
        }
#pragma unroll
        for (int off = 1; off < TPH; off <<= 1) {
            ps += __shfl_xor(ps, off);
            pd += __shfl_xor(pd, off);
        }
        if ((tx % TPH) == 0 && grow < n) {
            alS[(size_t)grow * H + h] = ps;
            alD[(size_t)grow * H + h] = pd;
        }
    }
}

// ---------------------------------------------------------------------------
// wave-per-destination aggregation (no-max softmax, fp16 gather) + BN + ELU
//   Out[d, :] = elu(bn( sum_e softmax(e)_e * h[src_e, :] + bias ))
// Phase-2 (H=4): a 256B fp16 row spans 32 lanes x 8B -> lane-halves process
// adjacent edge slots; each lane owns 4 channels (dwordx2/edge-pair, fma_mix).
// Phase-2 (H=1): 64B row spans 8 lanes -> 8 edge slots per load round.
// Accumulators combined across lane groups once in the epilogue.
// Logits are bounded (|e| <~ 10): exp() without max subtraction is safe and
// mathematically identical to max-subtracted softmax.
// NOTE: NW=4 destinations per block — grid must be ceil(n/4) for ALL H.
// ---------------------------------------------------------------------------
template <int H, int C>
__global__ __launch_bounds__(256) void gat_aggregate(
    const uint32* __restrict__ Hb,            // fp16-packed h, row = H*C/2 uints
    const int* __restrict__ rowptr, const int* __restrict__ esrc,
    const float* __restrict__ alS, const float* __restrict__ alD,
    const float* __restrict__ bias, const float* __restrict__ gamma,
    const float* __restrict__ beta, const float* __restrict__ bnmean,
    const float* __restrict__ bnvar, float* __restrict__ Out, int n) {
    constexpr int F  = H * C;                 // 128 or 32
    constexpr int RW = F / 2;                 // uints per row: 64 or 16
    constexpr int NW = 4;
    // plane stride 68: head-plane h starts at bank 4h -> the 8 simultaneous
    // broadcast addresses in phase-2 (4 heads x 2 halves) hit distinct banks.
    __shared__ __align__(16) int   s_src[NW][68];
    __shared__ __align__(16) float s_ex[NW][H][68];

    const int wave = threadIdx.x >> 6;
    const int lane = threadIdx.x & 63;
    const int d    = blockIdx.x * NW + wave;
    if (d >= n) return;                       // only wave-level barriers below

    const int beg = rowptr[d], end = rowptr[d + 1];
    float al_d[H], sl[H];
#pragma unroll
    for (int h = 0; h < H; ++h) {
        al_d[h] = alD[(size_t)d * H + h];
        sl[h]   = 0.f;
    }
    float acc[4] = {0.f, 0.f, 0.f, 0.f};
    // H=4 mapping: half = edge parity, q = channel quad (4q..4q+3), head=q>>3
    const int half = lane >> 5;
    const int q    = lane & 31;
    const int head = (H == 4) ? (q >> 3) : 0;
    // H=1 mapping: g8 = edge sub-slot (8 per round), q8 = channel quad
    const int g8 = lane >> 3;
    const int q8 = lane & 7;

    for (int base = beg; base < end; base += 64) {
        const int j   = base + lane;
        const bool act = (j < end);
        int sj = 0;
        float ex[H];
        if (act) {
            sj = esrc[j];
            if constexpr (H == 4) {
                float4 av = *(const float4*)(alS + (size_t)sj * 4);
                float t0 = av.x + al_d[0], t1 = av.y + al_d[1];
                float t2 = av.z + al_d[2], t3 = av.w + al_d[3];
                t0 = t0 > 0.f ? t0 : 0.2f * t0;
                t1 = t1 > 0.f ? t1 : 0.2f * t1;
                t2 = t2 > 0.f ? t2 : 0.2f * t2;
                t3 = t3 > 0.f ? t3 : 0.2f * t3;
                ex[0] = __expf(t0); ex[1] = __expf(t1);
                ex[2] = __expf(t2); ex[3] = __expf(t3);
            } else {
                float t0 = alS[sj] + al_d[0];
                t0 = t0 > 0.f ? t0 : 0.2f * t0;
                ex[0] = __expf(t0);
            }
        } else {
#pragma unroll
            for (int h = 0; h < H; ++h) ex[h] = 0.f;
        }
#pragma unroll
        for (int h = 0; h < H; ++h) {
            s_ex[wave][h][lane] = ex[h];
            sl[h] += ex[h];
        }
        s_src[wave][lane] = sj;                // 0 for inactive slots
        __builtin_amdgcn_wave_barrier();

        const int cc  = min(64, end - base);
        const int ccr = (cc + 7) & ~7;         // slots beyond cc carry weight 0
        if constexpr (H == 4) {
            for (int jj = 0; jj < ccr; jj += 8) {
                const int i0 = jj + half,     i1 = jj + 2 + half;
                const int i2 = jj + 4 + half, i3 = jj + 6 + half;
                const int   s0 = s_src[wave][i0], s1 = s_src[wave][i1];
                const int   s2 = s_src[wave][i2], s3 = s_src[wave][i3];
                const float w0 = s_ex[wave][head][i0], w1 = s_ex[wave][head][i1];
                const float w2 = s_ex[wave][head][i2], w3 = s_ex[wave][head][i3];
                const uint2 v0 = *(const uint2*)(Hb + (size_t)s0 * RW + q * 2);
                const uint2 v1 = *(const uint2*)(Hb + (size_t)s1 * RW + q * 2);
                const uint2 v2 = *(const uint2*)(Hb + (size_t)s2 * RW + q * 2);
                const uint2 v3 = *(const uint2*)(Hb + (size_t)s3 * RW + q * 2);
                fmah4(acc, v0, w0);
                fmah4(acc, v1, w1);
                fmah4(acc, v2, w2);
                fmah4(acc, v3, w3);
            }
        } else {
            for (int jj = 0; jj < ccr; jj += 8) {
                const int   idx = jj + g8;     // <= 63
                const int   s0  = s_src[wave][idx];
                const float w0  = s_ex[wave][0][idx];
                const uint2 v   = *(const uint2*)(Hb + (size_t)s0 * RW + q8 * 2);
                fmah4(acc, v, w0);
            }
        }
        __builtin_amdgcn_wave_barrier();
    }

    // reduce exp-sums across the wave (inactive lanes contributed 0)
#pragma unroll
    for (int h = 0; h < H; ++h) {
#pragma unroll
        for (int off = 32; off > 0; off >>= 1) sl[h] += __shfl_xor(sl[h], off);
    }

    if constexpr (H == 4) {
        // combine the two edge-parity halves; lanes 0..31 hold channels 4q..4q+3
#pragma unroll
        for (int j = 0; j < 4; ++j) acc[j] += __shfl_xor(acc[j], 32);
        if (lane < 32) {
            float a = (q & 8)  ? sl[1] : sl[0];
            float b = (q & 8)  ? sl[3] : sl[2];
            const float sh  = (q & 16) ? b : a;
            const float inv = 1.f / (sh + 1e-16f);
            const int c0 = q * 4;
            const float4 bi = *(const float4*)(bias + c0);
            const float4 mn = *(const float4*)(bnmean + c0);
            const float4 vr = *(const float4*)(bnvar + c0);
            const float4 gm = *(const float4*)(gamma + c0);
            const float4 bt = *(const float4*)(beta + c0);
            const float bia[4] = {bi.x, bi.y, bi.z, bi.w};
            const float mna[4] = {mn.x, mn.y, mn.z, mn.w};
            const float vra[4] = {vr.x, vr.y, vr.z, vr.w};
            const float gma[4] = {gm.x, gm.y, gm.z, gm.w};
            const float bta[4] = {bt.x, bt.y, bt.z, bt.w};
            float y[4];
#pragma unroll
            for (int jj = 0; jj < 4; ++jj) {
                const float o = acc[jj] * inv;
                float yy = (o + bia[jj] - mna[jj]) * rsqrtf(vra[jj] + 1e-5f) * gma[jj] + bta[jj];
                y[jj] = yy > 0.f ? yy : expm1f(yy);
            }
            *(float4*)(Out + (size_t)d * 128 + c0) = make_float4(y[0], y[1], y[2], y[3]);
        }
    } else {
        // combine the 8 edge sub-slot groups; lanes 0..7 hold channels 4q8..4q8+3
#pragma unroll
        for (int j = 0; j < 4; ++j) {
            acc[j] += __shfl_xor(acc[j], 8);
            acc[j] += __shfl_xor(acc[j], 16);
            acc[j] += __shfl_xor(acc[j], 32);
        }
        if (lane < 8) {
            const float inv = 1.f / (sl[0] + 1e-16f);
            const int c0 = q8 * 4;
            const float4 bi = *(const float4*)(bias + c0);
            const float4 mn = *(const float4*)(bnmean + c0);
            const float4 vr = *(const float4*)(bnvar + c0);
            const float4 gm = *(const float4*)(gamma + c0);
            const float4 bt = *(const float4*)(beta + c0);
            const float bia[4] = {bi.x, bi.y, bi.z, bi.w};
            const float mna[4] = {mn.x, mn.y, mn.z, mn.w};
            const float vra[4] = {vr.x, vr.y, vr.z, vr.w};
            const float gma[4] = {gm.x, gm.y, gm.z, gm.w};
            const float bta[4] = {bt.x, bt.y, bt.z, bt.w};
            float y[4];
#pragma unroll
            for (int jj = 0; jj < 4; ++jj) {
                const float o = acc[jj] * inv;
                float yy = (o + bia[jj] - mna[jj]) * rsqrtf(vra[jj] + 1e-5f) * gma[jj] + bta[jj];
                y[jj] = yy > 0.f ? yy : expm1f(yy);
            }
            *(float4*)(Out + (size_t)d * 32 + c0) = make_float4(y[0], y[1], y[2], y[3]);
        }
    }
}

// ---------------------------------------------------------------------------
// classifier: out[n, 10] = H3[n, 32] @ Wc[32, 10] + bc
// ---------------------------------------------------------------------------
__global__ void classifier_kernel(const float* __restrict__ H3, const float* __restrict__ Wc,
                                  const float* __restrict__ bc, float* __restrict__ out, int n) {
    int t  = blockIdx.x * blockDim.x + threadIdx.x;
    int ni = t / NCLS, c = t % NCLS;
    if (ni >= n) return;
    const float* row = H3 + (size_t)ni * HID;
    float a = bc[c];
#pragma unroll
    for (int k = 0; k < HID; ++k) a = fmaf(row[k], Wc[k * NCLS + c], a);
    out[(size_t)ni * NCLS + c] = a;
}

// ---------------------------------------------------------------------------
// launch
// ---------------------------------------------------------------------------
static inline char* align256(char* p) {
    return (char*)(((uintptr_t)p + 255) & ~(uintptr_t)255);
}

extern "C" void kernel_launch(void* const* d_in, const int* in_sizes, int n_in,
                              void* d_out, int out_size, void* d_ws, size_t ws_size,
                              hipStream_t stream) {
    const float* x  = (const float*)d_in[0];
    const int*   ei = (const int*)d_in[1];
    const int N = in_sizes[0] / FIN;
    const int E = in_sizes[1] / 2;
    const int* src = ei;
    const int* dst = ei + E;

    const float *W0 = (const float*)d_in[2],  *as0 = (const float*)d_in[3],
                *ad0 = (const float*)d_in[4], *b0 = (const float*)d_in[5],
                *g0 = (const float*)d_in[6],  *bt0 = (const float*)d_in[7],
                *m0 = (const float*)d_in[8],  *v0 = (const float*)d_in[9];
    const float *W1 = (const float*)d_in[10], *as1 = (const float*)d_in[11],
                *ad1 = (const float*)d_in[12],*b1 = (const float*)d_in[13],
                *g1 = (const float*)d_in[14], *bt1 = (const float*)d_in[15],
                *m1 = (const float*)d_in[16], *v1 = (const float*)d_in[17];
    const float *W2 = (const float*)d_in[18], *as2 = (const float*)d_in[19],
                *ad2 = (const float*)d_in[20],*b2 = (const float*)d_in[21],
                *g2 = (const float*)d_in[22], *bt2 = (const float*)d_in[23],
                *m2 = (const float*)d_in[24], *v2 = (const float*)d_in[25];
    const float *Wc = (const float*)d_in[26], *bc = (const float*)d_in[27];
    float* out = (float*)d_out;

    // workspace carve
    char* p = (char*)d_ws;
    uint32* Abf = (uint32*)p;   p = align256(p + (size_t)N * FIN * 2);   // gemm out fp16
    float* B = (float*)p;       p = align256(p + (size_t)N * FIN * 4);   // layer act out
    float* alS = (float*)p;     p = align256(p + (size_t)N * NHEADS * 4);
    float* alD = (float*)p;     p = align256(p + (size_t)N * NHEADS * 4);
    int* cnt = (int*)p;         p = align256(p + (size_t)N * 4);
    int* rowptr = (int*)p;      p = align256(p + (size_t)(N + 1) * 4);
    int* rank = (int*)p;        p = align256(p + (size_t)E * 4);
    int* esrc = (int*)p;        p = align256(p + (size_t)E * 4);
    int* bsum = (int*)p;        p = align256(p + 512 * 4);
    int* boff = (int*)p;        p = align256(p + 512 * 4);
    (void)ws_size; (void)n_in; (void)out_size;

    const int NB = (N + 255) / 256;
    const int EB4 = (E + 1023) / 1024;   // 4 edges/thread kernels

    // ---- CSR build (once; shared by all 3 layers) ----
    zero_i32<<<NB, 256, 0, stream>>>(cnt, N);
    hist_rank_kernel<<<EB4, 256, 0, stream>>>(dst, cnt, rank, E);
    scan_block_sums<<<NB, 256, 0, stream>>>(cnt, bsum, N);
    scan_single<<<1, 512, 0, stream>>>(bsum, boff, NB);
    scan_final<<<NB, 256, 0, stream>>>(cnt, boff, rowptr, N);
    scatter_kernel<<<EB4, 256, 0, stream>>>(src, dst, rank, rowptr, esrc, E);

    const int GB = (N + 127) / 128;
    const int AB = (N + 3) / 4;          // aggregate blocks: 4 dst per block

    // ---- layer 0 ----
    gemm_tiled<128, 4><<<GB, 256, 0, stream>>>(x, W0, as0, ad0, alS, alD, Abf, N);
    gat_aggregate<4, 32><<<AB, 256, 0, stream>>>(Abf, rowptr, esrc, alS, alD,
                                                 b0, g0, bt0, m0, v0, B, N);
    // ---- layer 1 ----
    gemm_tiled<128, 4><<<GB, 256, 0, stream>>>(B, W1, as1, ad1, alS, alD, Abf, N);
    gat_aggregate<4, 32><<<AB, 256, 0, stream>>>(Abf, rowptr, esrc, alS, alD,
                                                 b1, g1, bt1, m1, v1, B, N);
    // ---- layer 2 (single head, C=32) ----
    gemm_tiled<32, 1><<<GB, 256, 0, stream>>>(B, W2, as2, ad2, alS, alD, Abf, N);
    gat_aggregate<1, 32><<<AB, 256, 0, stream>>>(Abf, rowptr, esrc, alS, alD,
                                                 b2, g2, bt2, m2, v2, B, N);
    // ---- classifier ----
    classifier_kernel<<<(N * NCLS + 255) / 256, 256, 0, stream>>>(B, Wc, bc, out, N);
}

// Round 11
// 551.745 us; speedup vs baseline: 1.0708x; 1.0708x over previous
//
#include <hip/hip_runtime.h>
#include <hip/hip_bf16.h>
#include <math.h>

// Problem constants (match reference setup_inputs)
#define NN   100000
#define NE   1600000
#define FIN  128
#define HID  32
#define NHEADS 4
#define NCLS 10

typedef unsigned int uint32;
typedef __fp16 half2_t __attribute__((ext_vector_type(2)));
typedef __fp16 half8_t __attribute__((ext_vector_type(8)));
typedef float  f32x4   __attribute__((ext_vector_type(4)));

// pack 2 fp32 -> packed fp16 pair (v_cvt_pkrtz_f16_f32, 1 inst)
__device__ __forceinline__ uint32 packh2(float a, float b) {
    half2_t h = __builtin_amdgcn_cvt_pkrtz(a, b);
    return __builtin_bit_cast(uint32, h);
}
__device__ __forceinline__ float h_lo(uint32 v) {
    return (float)__builtin_bit_cast(half2_t, v)[0];
}
__device__ __forceinline__ float h_hi(uint32 v) {
    return (float)__builtin_bit_cast(half2_t, v)[1];
}
__device__ __forceinline__ half8_t as_h8(uint4 v) {
    return __builtin_bit_cast(half8_t, v);
}

// ---------------------------------------------------------------------------
// CSR build kernels
// ---------------------------------------------------------------------------
__global__ void zero_i32(int* __restrict__ p, int n) {
    int i = blockIdx.x * blockDim.x + threadIdx.x;
    if (i < n) p[i] = 0;
}

__global__ void hist_rank_kernel(const int* __restrict__ dst, int* __restrict__ cnt,
                                 int* __restrict__ rank, int e) {
    const int t0 = blockIdx.x * (blockDim.x * 4) + threadIdx.x;
    int d[4];
    bool a[4];
#pragma unroll
    for (int k = 0; k < 4; ++k) {
        const int j = t0 + k * 256;
        a[k] = (j < e);
        d[k] = a[k] ? dst[j] : 0;
    }
    int r[4];
#pragma unroll
    for (int k = 0; k < 4; ++k)
        if (a[k]) r[k] = atomicAdd(&cnt[d[k]], 1);
#pragma unroll
    for (int k = 0; k < 4; ++k) {
        const int j = t0 + k * 256;
        if (a[k]) rank[j] = r[k];
    }
}

__global__ void scan_block_sums(const int* __restrict__ cnt, int* __restrict__ bsum, int n) {
    __shared__ int sm[256];
    int i = blockIdx.x * 256 + threadIdx.x;
    int v = (i < n) ? cnt[i] : 0;
    sm[threadIdx.x] = v;
    __syncthreads();
    for (int off = 128; off > 0; off >>= 1) {
        if (threadIdx.x < off) sm[threadIdx.x] += sm[threadIdx.x + off];
        __syncthreads();
    }
    if (threadIdx.x == 0) bsum[blockIdx.x] = sm[0];
}

__global__ void scan_single(const int* __restrict__ bsum, int* __restrict__ boff, int nb) {
    __shared__ int sm[512];
    int t = threadIdx.x;
    int v = (t < nb) ? bsum[t] : 0;
    sm[t] = v;
    __syncthreads();
    for (int off = 1; off < 512; off <<= 1) {
        int u = (t >= off) ? sm[t - off] : 0;
        __syncthreads();
        sm[t] += u;
        __syncthreads();
    }
    if (t < nb) boff[t] = sm[t] - v;   // exclusive
}

__global__ void scan_final(const int* __restrict__ cnt, const int* __restrict__ boff,
                           int* __restrict__ rowptr, int n) {
    __shared__ int sm[256];
    int i = blockIdx.x * 256 + threadIdx.x;
    int v = (i < n) ? cnt[i] : 0;
    sm[threadIdx.x] = v;
    __syncthreads();
    for (int off = 1; off < 256; off <<= 1) {
        int u = (threadIdx.x >= off) ? sm[threadIdx.x - off] : 0;
        __syncthreads();
        sm[threadIdx.x] += u;
        __syncthreads();
    }
    int incl = sm[threadIdx.x];
    int excl = incl - v;
    if (i < n) rowptr[i] = boff[blockIdx.x] + excl;
    if (i == n - 1) rowptr[n] = boff[blockIdx.x] + incl;  // == E
}

__global__ void scatter_kernel(const int* __restrict__ src, const int* __restrict__ dst,
                               const int* __restrict__ rank, const int* __restrict__ rowptr,
                               int* __restrict__ esrc, int e) {
    const int t0 = blockIdx.x * (blockDim.x * 4) + threadIdx.x;
#pragma unroll
    for (int k = 0; k < 4; ++k) {
        const int j = t0 + k * 256;
        if (j < e) {
            const int d = dst[j];
            esrc[rowptr[d] + rank[j]] = src[j];
        }
    }
}

// ---------------------------------------------------------------------------
// conversions: fp32 -> packed fp16
// ---------------------------------------------------------------------------
// x[N,128] fp32 -> Xh[N,64] packed; thread handles 4 floats
__global__ void conv_x_kernel(const float* __restrict__ x, uint32* __restrict__ Xh, int n4) {
    int i = blockIdx.x * blockDim.x + threadIdx.x;
    if (i >= n4) return;
    const float4 v = ((const float4*)x)[i];
    ((uint2*)Xh)[i] = make_uint2(packh2(v.x, v.y), packh2(v.z, v.w));
}

// W[k][FOUT] fp32 -> Wt[n][k/2] packed fp16 (transposed). All 3 weights in one launch.
__global__ void conv_w_kernel(const float* __restrict__ W0, const float* __restrict__ W1,
                              const float* __restrict__ W2, uint32* __restrict__ Wt0,
                              uint32* __restrict__ Wt1, uint32* __restrict__ Wt2) {
    int t = blockIdx.x * blockDim.x + threadIdx.x;   // < 8192+8192+2048
    if (t < 8192) {
        const int nn = t >> 6, ku = t & 63;
        Wt0[t] = packh2(W0[(2 * ku) * 128 + nn], W0[(2 * ku + 1) * 128 + nn]);
    } else if (t < 16384) {
        const int l = t - 8192;
        const int nn = l >> 6, ku = l & 63;
        Wt1[l] = packh2(W1[(2 * ku) * 128 + nn], W1[(2 * ku + 1) * 128 + nn]);
    } else if (t < 18432) {
        const int l = t - 16384;
        const int nn = l >> 6, ku = l & 63;
        Wt2[l] = packh2(W2[(2 * ku) * 32 + nn], W2[(2 * ku + 1) * 32 + nn]);
    }
}

// ---------------------------------------------------------------------------
// MFMA GEMM (fp16 in, fp32 acc) + fused attention-logit epilogue.
//   Outh[n][FOUT/2] = fp16( Xh @ W )  (packed pairs)
//   alS/alD[n][H]   = per-head logit dots (fp32, from accumulators)
// Fragment layouts (gfx950 16x16x32, verified m89/m91/m120):
//   A: lane holds A[m=lane&15][k=quad*8+j]  (8 contiguous k -> uint4 of row)
//   B: lane holds B[k=quad*8+j][n=lane&15]  (contiguous in Wt[n][k])
//   D: lane holds D[row=quad*4+reg][col=lane&15]
// No LDS, no barriers: A streamed from global, B from L2-resident Wt.
// ---------------------------------------------------------------------------
template <int FOUT, int H>
__global__ __launch_bounds__(256) void gemm_mfma(const uint32* __restrict__ Xh,
                                                 const uint32* __restrict__ Wt,
                                                 const float* __restrict__ a_s,
                                                 const float* __restrict__ a_d,
                                                 float* __restrict__ alS,
                                                 float* __restrict__ alD,
                                                 uint32* __restrict__ Outh, int n) {
    constexpr int NT = FOUT / 16;            // 8 or 2 n-tiles
    const int wave = threadIdx.x >> 6;
    const int lane = threadIdx.x & 63;
    const int c = lane & 15;                 // D col / A load row / B col
    const int q = lane >> 4;                 // quad
    const int row0 = blockIdx.x * 128 + wave * 32;

    int r0 = row0 + c;
    int r1 = row0 + 16 + c;
    if (r0 >= n) r0 = n - 1;
    if (r1 >= n) r1 = n - 1;

    f32x4 acc[2][NT];
#pragma unroll
    for (int m = 0; m < 2; ++m)
#pragma unroll
        for (int nt = 0; nt < NT; ++nt) acc[m][nt] = (f32x4){0.f, 0.f, 0.f, 0.f};

    const uint4* XU = (const uint4*)Xh;
    const uint4* WU = (const uint4*)Wt;

#pragma unroll
    for (int ks = 0; ks < 4; ++ks) {
        const half8_t a0 = as_h8(XU[(size_t)r0 * 16 + ks * 4 + q]);
        const half8_t a1 = as_h8(XU[(size_t)r1 * 16 + ks * 4 + q]);
#pragma unroll
        for (int nt = 0; nt < NT; ++nt) {
            const half8_t b = as_h8(WU[(nt * 16 + c) * 16 + ks * 4 + q]);
            acc[0][nt] = __builtin_amdgcn_mfma_f32_16x16x32_f16(a0, b, acc[0][nt], 0, 0, 0);
            acc[1][nt] = __builtin_amdgcn_mfma_f32_16x16x32_f16(a1, b, acc[1][nt], 0, 0, 0);
        }
    }

    // a_s/a_d values for my columns (flat [H*C] == flat col index)
    float asv[NT], adv[NT];
#pragma unroll
    for (int nt = 0; nt < NT; ++nt) {
        asv[nt] = a_s[c + 16 * nt];
        adv[nt] = a_d[c + 16 * nt];
    }

#pragma unroll
    for (int m = 0; m < 2; ++m) {
#pragma unroll
        for (int reg = 0; reg < 4; ++reg) {
            const int grow = row0 + m * 16 + q * 4 + reg;
            const bool ok = (grow < n);
            // ---- fused logits: per-head partial dot, reduce over 16-lane row group
            if constexpr (H == 4) {
                float ps[4], pd[4];
#pragma unroll
                for (int h = 0; h < 4; ++h) {
                    ps[h] = acc[m][2 * h][reg] * asv[2 * h] + acc[m][2 * h + 1][reg] * asv[2 * h + 1];
                    pd[h] = acc[m][2 * h][reg] * adv[2 * h] + acc[m][2 * h + 1][reg] * adv[2 * h + 1];
                }
#pragma unroll
                for (int off = 1; off < 16; off <<= 1) {
#pragma unroll
                    for (int h = 0; h < 4; ++h) {
                        ps[h] += __shfl_xor(ps[h], off);
                        pd[h] += __shfl_xor(pd[h], off);
                    }
                }
                if (c < 4 && ok) {
                    const float vs = (c == 0) ? ps[0] : (c == 1) ? ps[1] : (c == 2) ? ps[2] : ps[3];
                    const float vd = (c == 0) ? pd[0] : (c == 1) ? pd[1] : (c == 2) ? pd[2] : pd[3];
                    alS[(size_t)grow * 4 + c] = vs;
                    alD[(size_t)grow * 4 + c] = vd;
                }
            } else {
                float ps = acc[m][0][reg] * asv[0] + acc[m][1][reg] * asv[1];
                float pd = acc[m][0][reg] * adv[0] + acc[m][1][reg] * adv[1];
#pragma unroll
                for (int off = 1; off < 16; off <<= 1) {
                    ps += __shfl_xor(ps, off);
                    pd += __shfl_xor(pd, off);
                }
                if (c == 0 && ok) {
                    alS[grow] = ps;
                    alD[grow] = pd;
                }
            }
            // ---- fp16-packed C store: pair col c with c^1, even lanes write
#pragma unroll
            for (int nt = 0; nt < NT; ++nt) {
                const float v = acc[m][nt][reg];
                const float o = __shfl_xor(v, 1);
                if (((c & 1) == 0) && ok) {
                    Outh[(size_t)grow * (FOUT / 2) + nt * 8 + (c >> 1)] = packh2(v, o);
                }
            }
        }
    }
}

// ---------------------------------------------------------------------------
// wave-per-destination aggregation (no-max softmax, fp16 gather) + BN + ELU
//   B16[d][F/2] = fp16( elu(bn( sum_e softmax(e)_e * h[src_e,:] + bias )) )
// Phase-2 (H=4): 8 edges/step; wave-uniform src -> readfirstlane -> SGPR base
// + lane offset (dword = 2 channels/lane); fp16 unpack folds into v_fma_mix.
// Phase-2 (H=1): 4 edges/iteration via 16-lane groups (row is 64 B).
// Logits bounded (|e| <~ 10): exp() without max subtraction is exact softmax.
// NOTE: NW=4 destinations per block — grid must be ceil(n/4) for ALL H.
// ---------------------------------------------------------------------------
template <int H, int C>
__global__ __launch_bounds__(256) void gat_aggregate(
    const uint32* __restrict__ Hb,            // fp16-packed h, row = H*C/2 uints
    const int* __restrict__ rowptr, const int* __restrict__ esrc,
    const float* __restrict__ alS, const float* __restrict__ alD,
    const float* __restrict__ bias, const float* __restrict__ gamma,
    const float* __restrict__ beta, const float* __restrict__ bnmean,
    const float* __restrict__ bnvar, uint32* __restrict__ B16, int n) {
    constexpr int F  = H * C;                 // 128 or 32
    constexpr int RW = F / 2;                 // uints per row: 64 or 16
    constexpr int NW = 4;
    __shared__ __align__(16) int   s_src[NW][68];
    __shared__ __align__(16) float s_ex[NW][H][68];

    const int wave = threadIdx.x >> 6;
    const int lane = threadIdx.x & 63;
    const int d    = blockIdx.x * NW + wave;
    if (d >= n) return;                       // only wave-level barriers below

    if (lane < 4) {
        s_src[wave][64 + lane] = 0;
#pragma unroll
        for (int h = 0; h < H; ++h) s_ex[wave][h][64 + lane] = 0.f;
    }
    __builtin_amdgcn_wave_barrier();

    const int beg = rowptr[d], end = rowptr[d + 1];
    float al_d[H], sl[H];
#pragma unroll
    for (int h = 0; h < H; ++h) {
        al_d[h] = alD[(size_t)d * H + h];
        sl[h]   = 0.f;
    }
    float acc0 = 0.f, acc1 = 0.f;
    const int head = (H == 4) ? (lane >> 4) : 0;

    for (int base = beg; base < end; base += 64) {
        const int j   = base + lane;
        const bool act = (j < end);
        int sj = 0;
        float ex[H];
        if (act) {
            sj = esrc[j];
            if constexpr (H == 4) {
                float4 av = *(const float4*)(alS + (size_t)sj * 4);
                float t0 = av.x + al_d[0], t1 = av.y + al_d[1];
                float t2 = av.z + al_d[2], t3 = av.w + al_d[3];
                t0 = t0 > 0.f ? t0 : 0.2f * t0;
                t1 = t1 > 0.f ? t1 : 0.2f * t1;
                t2 = t2 > 0.f ? t2 : 0.2f * t2;
                t3 = t3 > 0.f ? t3 : 0.2f * t3;
                ex[0] = __expf(t0); ex[1] = __expf(t1);
                ex[2] = __expf(t2); ex[3] = __expf(t3);
            } else {
                float t0 = alS[sj] + al_d[0];
                t0 = t0 > 0.f ? t0 : 0.2f * t0;
                ex[0] = __expf(t0);
            }
        } else {
#pragma unroll
            for (int h = 0; h < H; ++h) ex[h] = 0.f;
        }
#pragma unroll
        for (int h = 0; h < H; ++h) {
            s_ex[wave][h][lane] = ex[h];
            sl[h] += ex[h];
        }
        s_src[wave][lane] = sj;
        __builtin_amdgcn_wave_barrier();

        const int cc = min(64, end - base);
        if constexpr (H == 4) {
            const int ccr = (cc + 7) & ~7;    // slots beyond cc carry weight 0
            for (int jj = 0; jj < ccr; jj += 8) {
                const int4   sa = *(const int4*)  &s_src[wave][jj];
                const int4   sb = *(const int4*)  &s_src[wave][jj + 4];
                const float4 wa = *(const float4*)&s_ex[wave][head][jj];
                const float4 wb = *(const float4*)&s_ex[wave][head][jj + 4];
                const int b0 = __builtin_amdgcn_readfirstlane(sa.x);
                const int b1 = __builtin_amdgcn_readfirstlane(sa.y);
                const int b2 = __builtin_amdgcn_readfirstlane(sa.z);
                const int b3 = __builtin_amdgcn_readfirstlane(sa.w);
                const int b4 = __builtin_amdgcn_readfirstlane(sb.x);
                const int b5 = __builtin_amdgcn_readfirstlane(sb.y);
                const int b6 = __builtin_amdgcn_readfirstlane(sb.z);
                const int b7 = __builtin_amdgcn_readfirstlane(sb.w);
                const uint32 v0 = Hb[(size_t)b0 * RW + lane];  // SGPR base + voffset
                const uint32 v1 = Hb[(size_t)b1 * RW + lane];
                const uint32 v2 = Hb[(size_t)b2 * RW + lane];
                const uint32 v3 = Hb[(size_t)b3 * RW + lane];
                const uint32 v4 = Hb[(size_t)b4 * RW + lane];
                const uint32 v5 = Hb[(size_t)b5 * RW + lane];
                const uint32 v6 = Hb[(size_t)b6 * RW + lane];
                const uint32 v7 = Hb[(size_t)b7 * RW + lane];
                acc0 = fmaf(h_lo(v0), wa.x, acc0); acc1 = fmaf(h_hi(v0), wa.x, acc1);
                acc0 = fmaf(h_lo(v1), wa.y, acc0); acc1 = fmaf(h_hi(v1), wa.y, acc1);
                acc0 = fmaf(h_lo(v2), wa.z, acc0); acc1 = fmaf(h_hi(v2), wa.z, acc1);
                acc0 = fmaf(h_lo(v3), wa.w, acc0); acc1 = fmaf(h_hi(v3), wa.w, acc1);
                acc0 = fmaf(h_lo(v4), wb.x, acc0); acc1 = fmaf(h_hi(v4), wb.x, acc1);
                acc0 = fmaf(h_lo(v5), wb.y, acc0); acc1 = fmaf(h_hi(v5), wb.y, acc1);
                acc0 = fmaf(h_lo(v6), wb.z, acc0); acc1 = fmaf(h_hi(v6), wb.z, acc1);
                acc0 = fmaf(h_lo(v7), wb.w, acc0); acc1 = fmaf(h_hi(v7), wb.w, acc1);
            }
        } else {
            const int g  = lane >> 4;      // edge sub-slot
            const int li = lane & 15;      // uint within 16-uint row
            for (int jj = 0; jj < cc; jj += 4) {
                const int   idx = jj + g;              // <= 66, inside padding
                const int   sj2 = s_src[wave][idx];
                const float w   = s_ex[wave][0][idx];  // 0 beyond cc
                const uint32 v  = Hb[(size_t)sj2 * RW + li];
                acc0 = fmaf(h_lo(v), w, acc0);
                acc1 = fmaf(h_hi(v), w, acc1);
            }
        }
        __builtin_amdgcn_wave_barrier();
    }

    // reduce exp-sums across the wave (inactive lanes contributed 0)
#pragma unroll
    for (int h = 0; h < H; ++h) {
#pragma unroll
        for (int off = 32; off > 0; off >>= 1) sl[h] += __shfl_xor(sl[h], off);
    }
    float sh;
    if constexpr (H == 4) {
        float a = (head & 1) ? sl[1] : sl[0];
        float b = (head & 1) ? sl[3] : sl[2];
        sh = (head & 2) ? b : a;
    } else {
        sh = sl[0];
        acc0 += __shfl_xor(acc0, 16); acc0 += __shfl_xor(acc0, 32);
        acc1 += __shfl_xor(acc1, 16); acc1 += __shfl_xor(acc1, 32);
    }

    const float inv = 1.f / (sh + 1e-16f);
    const int li  = (F == 128) ? lane : (lane & 15);
    const int c0 = 2 * li, c1 = 2 * li + 1;
    const bool wr = (F == 128) || (lane < 16);
    if (wr) {
        float o0 = acc0 * inv, o1 = acc1 * inv;
        float y0 = (o0 + bias[c0] - bnmean[c0]) * rsqrtf(bnvar[c0] + 1e-5f) * gamma[c0] + beta[c0];
        float y1 = (o1 + bias[c1] - bnmean[c1]) * rsqrtf(bnvar[c1] + 1e-5f) * gamma[c1] + beta[c1];
        y0 = y0 > 0.f ? y0 : expm1f(y0);
        y1 = y1 > 0.f ? y1 : expm1f(y1);
        B16[(size_t)d * RW + li] = packh2(y0, y1);
    }
}

// ---------------------------------------------------------------------------
// classifier: out[n, 10] = fp16(H3)[n, 32] @ Wc[32, 10] + bc
// ---------------------------------------------------------------------------
__global__ void classifier_kernel(const uint32* __restrict__ H3, const float* __restrict__ Wc,
                                  const float* __restrict__ bc, float* __restrict__ out, int n) {
    int t  = blockIdx.x * blockDim.x + threadIdx.x;
    int ni = t / NCLS, c = t % NCLS;
    if (ni >= n) return;
    const uint32* row = H3 + (size_t)ni * 16;
    float a = bc[c];
#pragma unroll
    for (int u = 0; u < 16; ++u) {
        const uint32 v = row[u];
        a = fmaf(h_lo(v), Wc[(2 * u) * NCLS + c], a);
        a = fmaf(h_hi(v), Wc[(2 * u + 1) * NCLS + c], a);
    }
    out[(size_t)ni * NCLS + c] = a;
}

// ---------------------------------------------------------------------------
// launch
// ---------------------------------------------------------------------------
static inline char* align256(char* p) {
    return (char*)(((uintptr_t)p + 255) & ~(uintptr_t)255);
}

extern "C" void kernel_launch(void* const* d_in, const int* in_sizes, int n_in,
                              void* d_out, int out_size, void* d_ws, size_t ws_size,
                              hipStream_t stream) {
    const float* x  = (const float*)d_in[0];
    const int*   ei = (const int*)d_in[1];
    const int N = in_sizes[0] / FIN;
    const int E = in_sizes[1] / 2;
    const int* src = ei;
    const int* dst = ei + E;

    const float *W0 = (const float*)d_in[2],  *as0 = (const float*)d_in[3],
                *ad0 = (const float*)d_in[4], *b0 = (const float*)d_in[5],
                *g0 = (const float*)d_in[6],  *bt0 = (const float*)d_in[7],
                *m0 = (const float*)d_in[8],  *v0 = (const float*)d_in[9];
    const float *W1 = (const float*)d_in[10], *as1 = (const float*)d_in[11],
                *ad1 = (const float*)d_in[12],*b1 = (const float*)d_in[13],
                *g1 = (const float*)d_in[14], *bt1 = (const float*)d_in[15],
                *m1 = (const float*)d_in[16], *v1 = (const float*)d_in[17];
    const float *W2 = (const float*)d_in[18], *as2 = (const float*)d_in[19],
                *ad2 = (const float*)d_in[20],*b2 = (const float*)d_in[21],
                *g2 = (const float*)d_in[22], *bt2 = (const float*)d_in[23],
                *m2 = (const float*)d_in[24], *v2 = (const float*)d_in[25];
    const float *Wc = (const float*)d_in[26], *bc = (const float*)d_in[27];
    float* out = (float*)d_out;

    // workspace carve
    char* p = (char*)d_ws;
    uint32* Xh  = (uint32*)p;   p = align256(p + (size_t)N * 64 * 4);    // x fp16 (uint each)
    uint32* Ht  = (uint32*)p;   p = align256(p + (size_t)N * 64 * 4);    // gemm out fp16
    uint32* B16 = (uint32*)p;   p = align256(p + (size_t)N * 64 * 4);    // layer act fp16
    uint32* Wt0 = (uint32*)p;   p = align256(p + 8192 * 4);
    uint32* Wt1 = (uint32*)p;   p = align256(p + 8192 * 4);
    uint32* Wt2 = (uint32*)p;   p = align256(p + 2048 * 4);
    float* alS = (float*)p;     p = align256(p + (size_t)N * NHEADS * 4);
    float* alD = (float*)p;     p = align256(p + (size_t)N * NHEADS * 4);
    int* cnt = (int*)p;         p = align256(p + (size_t)N * 4);
    int* rowptr = (int*)p;      p = align256(p + (size_t)(N + 1) * 4);
    int* rank = (int*)p;        p = align256(p + (size_t)E * 4);
    int* esrc = (int*)p;        p = align256(p + (size_t)E * 4);
    int* bsum = (int*)p;        p = align256(p + 512 * 4);
    int* boff = (int*)p;        p = align256(p + 512 * 4);
    (void)ws_size; (void)n_in; (void)out_size;

    const int NB = (N + 255) / 256;
    const int EB4 = (E + 1023) / 1024;   // 4 edges/thread kernels

    // ---- CSR build (once; shared by all 3 layers) ----
    zero_i32<<<NB, 256, 0, stream>>>(cnt, N);
    hist_rank_kernel<<<EB4, 256, 0, stream>>>(dst, cnt, rank, E);
    scan_block_sums<<<NB, 256, 0, stream>>>(cnt, bsum, N);
    scan_single<<<1, 512, 0, stream>>>(bsum, boff, NB);
    scan_final<<<NB, 256, 0, stream>>>(cnt, boff, rowptr, N);
    scatter_kernel<<<EB4, 256, 0, stream>>>(src, dst, rank, rowptr, esrc, E);

    // ---- fp16 conversions ----
    conv_x_kernel<<<(N * 32 + 255) / 256, 256, 0, stream>>>(x, Xh, N * 32);
    conv_w_kernel<<<72, 256, 0, stream>>>(W0, W1, W2, Wt0, Wt1, Wt2);

    const int GB = (N + 127) / 128;
    const int AB = (N + 3) / 4;          // aggregate blocks: 4 dst per block

    // ---- layer 0 ----
    gemm_mfma<128, 4><<<GB, 256, 0, stream>>>(Xh, Wt0, as0, ad0, alS, alD, Ht, N);
    gat_aggregate<4, 32><<<AB, 256, 0, stream>>>(Ht, rowptr, esrc, alS, alD,
                                                 b0, g0, bt0, m0, v0, B16, N);
    // ---- layer 1 ----
    gemm_mfma<128, 4><<<GB, 256, 0, stream>>>(B16, Wt1, as1, ad1, alS, alD, Ht, N);
    gat_aggregate<4, 32><<<AB, 256, 0, stream>>>(Ht, rowptr, esrc, alS, alD,
                                                 b1, g1, bt1, m1, v1, B16, N);
    // ---- layer 2 (single head, C=32) ----
    gemm_mfma<32, 1><<<GB, 256, 0, stream>>>(B16, Wt2, as2, ad2, alS, alD, Ht, N);
    gat_aggregate<1, 32><<<AB, 256, 0, stream>>>(Ht, rowptr, esrc, alS, alD,
                                                 b2, g2, bt2, m2, v2, B16, N);
    // ---- classifier ----
    classifier_kernel<<<(N * NCLS + 255) / 256, 256, 0, stream>>>(B16, Wc, bc, out, N);
}